// Round 12
// baseline (840.883 us; speedup 1.0000x reference)
//
#include <hip/hip_runtime.h>

#define LN_EPS 1e-5f
// -(LR * 2/H) = -(0.01 * 2/32): folds SGD lr and MSE-mean gradient factor
#define C1 (-6.25e-4f)

typedef unsigned uint2v __attribute__((ext_vector_type(2)));

// ---------- cross-lane helpers (all VALU, no LDS) ----------
template<int CTRL>
__device__ __forceinline__ float dppAdd(float x) {
  int s = __builtin_amdgcn_update_dpp(0, __float_as_int(x), CTRL, 0xF, 0xF, true);
  return x + __int_as_float(s);
}

// Sum over each 32-lane half; result replicated within the half.
// 4 DPP stages (masks HW-validated r6/r7) + permlane16_swap via BUILTIN.
// Direction-robust: r.x + r.y equals (own-rowpair + other-rowpair) under
// either swap orientation.
__device__ __forceinline__ float redHalf(float x) {
  x = dppAdd<0xB1>(x);    // quad_perm(1,0,3,2): xor 1
  x = dppAdd<0x4E>(x);    // quad_perm(2,3,0,1): xor 2
  x = dppAdd<0x124>(x);   // row_ror:4 (quads uniform -> adds other quad pair)
  x = dppAdd<0x128>(x);   // row_ror:8 -> 16-row sums [R0,R1,R2,R3]
  uint2v r = __builtin_amdgcn_permlane16_swap(__float_as_uint(x),
                                              __float_as_uint(x),
                                              false, false);
  return __uint_as_float(r.x) + __uint_as_float(r.y);  // R(2k)+R(2k+1) repl.
}

// Value of x in the OTHER 32-lane half. Direction-robust: after the swap,
// {r.x, r.y} = {own, partner} in every lane (either order), so
// partner = r.x + r.y - x  (1e-7-level rounding, irrelevant here).
__device__ __forceinline__ float xchg32(float x) {
  uint2v r = __builtin_amdgcn_permlane32_swap(__float_as_uint(x),
                                              __float_as_uint(x),
                                              false, false);
  return (__uint_as_float(r.x) + __uint_as_float(r.y)) - x;
}

// ---------- kernel A: H[v] = LN(embed[v] + ff(embed[v])), H dim = 32 ----------
__global__ __launch_bounds__(64) void pmm_build_H(
    const float* __restrict__ embed,  // [64][32]
    const float* __restrict__ fw1,    // [64][32]
    const float* __restrict__ fb1,    // [64]
    const float* __restrict__ fw2,    // [32][64]
    const float* __restrict__ fb2,    // [32]
    const float* __restrict__ lng,    // [32]
    const float* __restrict__ lnb,    // [32]
    float* __restrict__ H) {          // [64][32]
  const int v = blockIdx.x;
  const int t = threadIdx.x;
  __shared__ float e[32];
  __shared__ float r1[64];
  if (t < 32) e[t] = embed[v * 32 + t];
  __syncthreads();
  float acc = fb1[t];
  #pragma unroll
  for (int h = 0; h < 32; ++h) acc = fmaf(e[h], fw1[t * 32 + h], acc);
  r1[t] = fmaxf(acc, 0.f);
  __syncthreads();
  if (t < 32) {
    float a2 = fb2[t];
    #pragma unroll
    for (int o = 0; o < 64; ++o) a2 = fmaf(r1[o], fw2[t * 64 + o], a2);
    float z = e[t] + a2;
    float s = z;
    #pragma unroll
    for (int m = 1; m < 32; m <<= 1) s += __shfl_xor(s, m, 64);
    float mu = s * (1.f / 32.f);
    float dz = z - mu;
    float q = dz * dz;
    #pragma unroll
    for (int m = 1; m < 32; m <<= 1) q += __shfl_xor(q, m, 64);
    float var = q * (1.f / 32.f);
    H[v * 32 + t] = dz / sqrtf(var + LN_EPS) * lng[t] + lnb[t];
  }
}

// ---------- kernel B: per-sample inner SGD loop, full 64-lane wave ----------
// Lanes l and l^32 both own column c=l&31 (mirrored k/v); half h=l>>5 owns
// hidden units i = 4h..4h+3. All cross-lane via DPP/permlane (zero LDS ops
// in the steady-state step).
__global__ __launch_bounds__(64) void pmm_inner(
    const void* __restrict__ seq_raw,   // int32 (int64 auto-detected)
    const float* __restrict__ H,        // [64][32] f32 table in ws
    const float* __restrict__ mw1,      // [8][32]
    const float* __restrict__ mb1,      // [8]
    const float* __restrict__ mw2,      // [32][8]
    const float* __restrict__ mb2,      // [32]
    const float* __restrict__ ow,       // [64][32]
    const float* __restrict__ ob,       // [64]
    float* __restrict__ out) {          // [256][64]
  const int b = blockIdx.x;
  const int l = threadIdx.x;    // 0..63
  const int c = l & 31;         // hidden column
  const int h = l >> 5;         // half: local hidden units 4h..4h+3

  __shared__ float Hs[64 * 32];    // 8 KB
  __shared__ int   seqs[4096];     // 16 KB: this sample's indices
  __shared__ float OWp[64 * 33];   // out_w, stride-33 padded
  __shared__ float ctxs[32];

  const int* __restrict__ s32 = (const int*)seq_raw;
  // int64 detection: values 0..63 => under int64 every odd int32 word of
  // sample 0 is zero. Reads first 16 KB only (safe for both widths).
  int accv = 0;
  #pragma unroll
  for (int q = 0; q < 32; ++q) accv |= s32[2 * (l * 32 + q) + 1];
  const bool is64 = (__ballot(accv != 0) == 0ULL);

  // stage this sample's seq slice
  const int base = b * 4096;
  if (!is64) {
    #pragma unroll
    for (int m = 0; m < 16; ++m)
      ((int4*)seqs)[m * 64 + l] = ((const int4*)(s32 + base))[m * 64 + l];
  } else {
    #pragma unroll
    for (int m = 0; m < 64; ++m)
      seqs[m * 64 + l] = s32[(base + m * 64 + l) << 1];  // low word (LE)
  }

  // stage H table: 2048 floats = 512 float4
  #pragma unroll
  for (int m = 0; m < 8; ++m)
    ((float4*)Hs)[m * 64 + l] = ((const float4*)H)[m * 64 + l];
  // stage out_w padded (elements of one float4 stay in one row: idx%32<=28)
  #pragma unroll
  for (int m = 0; m < 8; ++m) {
    float4 x = ((const float4*)ow)[m * 64 + l];
    const int idx = (m * 64 + l) * 4;
    const int r = idx >> 5, cc = idx & 31;
    OWp[r * 33 + cc]     = x.x;
    OWp[r * 33 + cc + 1] = x.y;
    OWp[r * 33 + cc + 2] = x.z;
    OWp[r * 33 + cc + 3] = x.w;
  }

  // per-lane parameters: local W1 rows, W2 row c in local-first order
  float W1L[4], B1L[4], W2o[8];
  #pragma unroll
  for (int j = 0; j < 4; ++j) {
    W1L[j] = mw1[(4 * h + j) * 32 + c];
    B1L[j] = mb1[4 * h + j];
  }
  #pragma unroll
  for (int j = 0; j < 8; ++j) {
    const int i = (j < 4) ? (4 * h + j) : (4 * (1 - h) + (j - 4));
    W2o[j] = mw2[c * 8 + i];   // j<4: local units, j>=4: remote units
  }
  float b2L = mb2[c];
  __syncthreads();

  auto PF = [&](int m, float2& kv) {
    const int ik = seqs[2 * m], iv = seqs[2 * m + 1];
    kv.x = Hs[ik * 32 + c];
    kv.y = Hs[iv * 32 + c];
  };

  auto STEP = [&](const float2& kv) {
    float z1[4], a1l[4], a1r[4];
    #pragma unroll
    for (int j = 0; j < 4; ++j) {
      z1[j] = redHalf(W1L[j] * kv.x) + B1L[j];  // w1[i].k + b1[i], i local
      a1l[j] = fmaxf(z1[j], 0.f);
    }
    #pragma unroll
    for (int j = 0; j < 4; ++j) a1r[j] = xchg32(a1l[j]);
    // r = pred[c] - v[c]; two 4-deep FMA chains then combine
    float rA = b2L, rB = -kv.y;
    #pragma unroll
    for (int j = 0; j < 4; ++j) {
      rA = fmaf(W2o[j],     a1l[j], rA);
      rB = fmaf(W2o[4 + j], a1r[j], rB);
    }
    const float r = rA + rB;
    float m8[4];                    // sum_c w2[c][i]*r_c, i local, OLD w2
    #pragma unroll
    for (int j = 0; j < 4; ++j) m8[j] = redHalf(W2o[j] * r);
    const float q = C1 * r;
    #pragma unroll
    for (int j = 0; j < 4; ++j) {
      W2o[j]     = fmaf(q, a1l[j], W2o[j]);
      W2o[4 + j] = fmaf(q, a1r[j], W2o[4 + j]);
    }
    b2L += q;
    #pragma unroll
    for (int j = 0; j < 4; ++j) {
      const float dl = (z1[j] > 0.f) ? C1 * m8[j] : 0.f;
      B1L[j] += dl;
      W1L[j] = fmaf(dl, kv.x, W1L[j]);
    }
  };

  // 2047 steps, 2-slot software pipeline (kv prefetched 1 step ahead)
  float2 s0, s1;
  PF(0, s0);
  for (int m = 0; m < 2046; m += 2) {
    PF(m + 1, s1);
    STEP(s0);
    PF(m + 2, s0);
    STEP(s1);
  }
  STEP(s0);  // step 2046

  // epilogue: ctx = mlp(final params, H[seq[4095]]); out = ctx @ ow^T + ob
  {
    const int ik = seqs[4095];
    const float kq = Hs[ik * 32 + c];
    float a1l[4], a1r[4];
    #pragma unroll
    for (int j = 0; j < 4; ++j)
      a1l[j] = fmaxf(redHalf(W1L[j] * kq) + B1L[j], 0.f);
    #pragma unroll
    for (int j = 0; j < 4; ++j) a1r[j] = xchg32(a1l[j]);
    float p = b2L;
    #pragma unroll
    for (int j = 0; j < 4; ++j) p = fmaf(W2o[j], a1l[j], p);
    #pragma unroll
    for (int j = 0; j < 4; ++j) p = fmaf(W2o[4 + j], a1r[j], p);
    if (l < 32) ctxs[c] = p;   // half A local order == global i order
    __syncthreads();
    float acc = ob[l];
    #pragma unroll
    for (int j = 0; j < 32; ++j) acc = fmaf(OWp[l * 33 + j], ctxs[j], acc);
    out[b * 64 + l] = acc;
  }
}

extern "C" void kernel_launch(void* const* d_in, const int* in_sizes, int n_in,
                              void* d_out, int out_size, void* d_ws, size_t ws_size,
                              hipStream_t stream) {
  const void*  seq   = d_in[0];
  const float* embed = (const float*)d_in[1];
  const float* fw1   = (const float*)d_in[2];
  const float* fb1   = (const float*)d_in[3];
  const float* fw2   = (const float*)d_in[4];
  const float* fb2   = (const float*)d_in[5];
  const float* lng   = (const float*)d_in[6];
  const float* lnb   = (const float*)d_in[7];
  const float* mw1   = (const float*)d_in[8];
  const float* mb1   = (const float*)d_in[9];
  const float* mw2   = (const float*)d_in[10];
  const float* mb2   = (const float*)d_in[11];
  const float* ow    = (const float*)d_in[12];
  const float* ob    = (const float*)d_in[13];
  float* out = (float*)d_out;
  float* H   = (float*)d_ws;  // 64*32 f32 table

  pmm_build_H<<<64, 64, 0, stream>>>(embed, fw1, fb1, fw2, fb2, lng, lnb, H);
  pmm_inner<<<256, 64, 0, stream>>>(seq, H, mw1, mb1, mw2, mb2, ow, ob, out);
}

// Round 13
// 775.104 us; speedup vs baseline: 1.0849x; 1.0849x over previous
//
#include <hip/hip_runtime.h>

#define LN_EPS 1e-5f
// -(LR * 2/H) = -(0.01 * 2/32): folds SGD lr and MSE-mean gradient factor
#define C1 (-6.25e-4f)

typedef unsigned uint2v __attribute__((ext_vector_type(2)));

// ---------- cross-lane helpers ----------
template<int CTRL>
__device__ __forceinline__ float dppAdd(float x) {
  int s = __builtin_amdgcn_update_dpp(0, __float_as_int(x), CTRL, 0xF, 0xF, true);
  return x + __int_as_float(s);
}

// Sum over each 32-lane half; replicated within the half. 4 DPP stages +
// ds_swizzle xor16 (exact r7-validated form: fastest measured variant).
__device__ __forceinline__ float redHalf(float x) {
  x = dppAdd<0xB1>(x);    // quad_perm(1,0,3,2): xor 1
  x = dppAdd<0x4E>(x);    // quad_perm(2,3,0,1): xor 2
  x = dppAdd<0x124>(x);   // row_ror:4
  x = dppAdd<0x128>(x);   // row_ror:8 -> 16-row sums
  x = x + __int_as_float(__builtin_amdgcn_ds_swizzle(__float_as_int(x), 0x401F)); // xor16
  return x;
}

// Value of x in the OTHER 32-lane half (r12-validated robust permlane form;
// pure VALU -> shortest latency for the single on-critical-path exchange).
__device__ __forceinline__ float xchg32(float x) {
  uint2v r = __builtin_amdgcn_permlane32_swap(__float_as_uint(x),
                                              __float_as_uint(x),
                                              false, false);
  return (__uint_as_float(r.x) + __uint_as_float(r.y)) - x;
}

// ---------- kernel A: H[v] = LN(embed[v] + ff(embed[v])), H dim = 32 ----------
__global__ __launch_bounds__(64) void pmm_build_H(
    const float* __restrict__ embed,  // [64][32]
    const float* __restrict__ fw1,    // [64][32]
    const float* __restrict__ fb1,    // [64]
    const float* __restrict__ fw2,    // [32][64]
    const float* __restrict__ fb2,    // [32]
    const float* __restrict__ lng,    // [32]
    const float* __restrict__ lnb,    // [32]
    float* __restrict__ H) {          // [64][32]
  const int v = blockIdx.x;
  const int t = threadIdx.x;
  __shared__ float e[32];
  __shared__ float r1[64];
  if (t < 32) e[t] = embed[v * 32 + t];
  __syncthreads();
  float acc = fb1[t];
  #pragma unroll
  for (int h = 0; h < 32; ++h) acc = fmaf(e[h], fw1[t * 32 + h], acc);
  r1[t] = fmaxf(acc, 0.f);
  __syncthreads();
  if (t < 32) {
    float a2 = fb2[t];
    #pragma unroll
    for (int o = 0; o < 64; ++o) a2 = fmaf(r1[o], fw2[t * 64 + o], a2);
    float z = e[t] + a2;
    float s = z;
    #pragma unroll
    for (int m = 1; m < 32; m <<= 1) s += __shfl_xor(s, m, 64);
    float mu = s * (1.f / 32.f);
    float dz = z - mu;
    float q = dz * dz;
    #pragma unroll
    for (int m = 1; m < 32; m <<= 1) q += __shfl_xor(q, m, 64);
    float var = q * (1.f / 32.f);
    H[v * 32 + t] = dz / sqrtf(var + LN_EPS) * lng[t] + lnb[t];
  }
}

// ---------- kernel B: per-sample inner SGD loop, full 64-lane wave ----------
// Lanes l and l^32 both own column c=l&31 (mirrored k/v); half h=l>>5 owns
// hidden units i = 4h..4h+3. Look-ahead z1: the W1.k_next and k.k_next
// reduces issue at iteration start (off the serial chain); z1_{m+1} =
// R1 + B1_m + dl_m*(s+1) — algebraically identical to the reference.
__global__ __launch_bounds__(64) void pmm_inner(
    const void* __restrict__ seq_raw,   // int32 (int64 auto-detected)
    const float* __restrict__ H,        // [64][32] f32 table in ws
    const float* __restrict__ mw1,      // [8][32]
    const float* __restrict__ mb1,      // [8]
    const float* __restrict__ mw2,      // [32][8]
    const float* __restrict__ mb2,      // [32]
    const float* __restrict__ ow,       // [64][32]
    const float* __restrict__ ob,       // [64]
    float* __restrict__ out) {          // [256][64]
  const int b = blockIdx.x;
  const int l = threadIdx.x;    // 0..63
  const int c = l & 31;         // hidden column
  const int h = l >> 5;         // half: local hidden units 4h..4h+3

  __shared__ float Hs[64 * 32];    // 8 KB
  __shared__ int   seqs[4096];     // 16 KB: this sample's indices
  __shared__ float OWp[64 * 33];   // out_w, stride-33 padded
  __shared__ float ctxs[32];

  const int* __restrict__ s32 = (const int*)seq_raw;
  // int64 detection: values 0..63 => under int64 every odd int32 word of
  // sample 0 is zero. Reads first 16 KB only (safe for both widths).
  int accv = 0;
  #pragma unroll
  for (int q = 0; q < 32; ++q) accv |= s32[2 * (l * 32 + q) + 1];
  const bool is64 = (__ballot(accv != 0) == 0ULL);

  // stage this sample's seq slice
  const int base = b * 4096;
  if (!is64) {
    #pragma unroll
    for (int m = 0; m < 16; ++m)
      ((int4*)seqs)[m * 64 + l] = ((const int4*)(s32 + base))[m * 64 + l];
  } else {
    #pragma unroll
    for (int m = 0; m < 64; ++m)
      seqs[m * 64 + l] = s32[(base + m * 64 + l) << 1];  // low word (LE)
  }

  // stage H table: 2048 floats = 512 float4
  #pragma unroll
  for (int m = 0; m < 8; ++m)
    ((float4*)Hs)[m * 64 + l] = ((const float4*)H)[m * 64 + l];
  // stage out_w padded (elements of one float4 stay in one row: idx%32<=28)
  #pragma unroll
  for (int m = 0; m < 8; ++m) {
    float4 x = ((const float4*)ow)[m * 64 + l];
    const int idx = (m * 64 + l) * 4;
    const int r = idx >> 5, cc = idx & 31;
    OWp[r * 33 + cc]     = x.x;
    OWp[r * 33 + cc + 1] = x.y;
    OWp[r * 33 + cc + 2] = x.z;
    OWp[r * 33 + cc + 3] = x.w;
  }

  // per-lane parameters: local W1 rows, LOCAL-i W2 entries only
  float W1L[4], B1L[4], W2o[4];
  #pragma unroll
  for (int j = 0; j < 4; ++j) {
    W1L[j] = mw1[(4 * h + j) * 32 + c];
    B1L[j] = mb1[4 * h + j];
    W2o[j] = mw2[c * 8 + 4 * h + j];
  }
  float b2L = mb2[c];
  __syncthreads();

  auto PF = [&](int m, float2& kv) {
    const int ik = seqs[2 * m], iv = seqs[2 * m + 1];
    kv.x = Hs[ik * 32 + c];
    kv.y = Hs[iv * 32 + c];
  };

  // One SGD step. z1 (for kvc) is carried in; on exit z1 holds next step's
  // preactivation (for kvn). Parameter updates identical to reference.
  auto STEP = [&](const float2& kvc, const float2& kvn, float* z1) {
    // look-ahead trees: only need step-start state (W1, k_cur, k_next)
    float s = redHalf(kvc.x * kvn.x);          // k_m . k_{m+1}
    float R1[4];
    #pragma unroll
    for (int j = 0; j < 4; ++j) R1[j] = redHalf(W1L[j] * kvn.x);
    // serial chain
    float a1l[4];
    #pragma unroll
    for (int j = 0; j < 4; ++j) a1l[j] = fmaxf(z1[j], 0.f);
    float pl = 0.f;                            // local-i partial of pred[c]
    #pragma unroll
    for (int j = 0; j < 4; ++j) pl = fmaf(W2o[j], a1l[j], pl);
    const float pr = xchg32(pl);               // remote-i partial
    const float r = (pl + pr) + (b2L - kvc.y); // identical in both halves
    float m8[4];                               // sum_c W2[c][i] r_c, i local
    #pragma unroll
    for (int j = 0; j < 4; ++j) m8[j] = redHalf(W2o[j] * r);
    const float q = C1 * r;
    #pragma unroll
    for (int j = 0; j < 4; ++j) W2o[j] = fmaf(q, a1l[j], W2o[j]);
    b2L += q;
    const float sp1 = s + 1.0f;
    #pragma unroll
    for (int j = 0; j < 4; ++j) {
      const float dl = (z1[j] > 0.f) ? C1 * m8[j] : 0.f;
      W1L[j] = fmaf(dl, kvc.x, W1L[j]);
      z1[j] = fmaf(dl, sp1, R1[j] + B1L[j]);   // z1 for next step (uses old B1)
      B1L[j] += dl;
    }
  };

  // prologue: direct z1 for step 0
  float2 kc;
  PF(0, kc);
  float z1[4];
  #pragma unroll
  for (int j = 0; j < 4; ++j) z1[j] = redHalf(W1L[j] * kc.x) + B1L[j];

  for (int m = 0; m < 2046; ++m) {
    float2 kn;
    PF(m + 1, kn);
    STEP(kc, kn, z1);
    kc = kn;
  }
  STEP(kc, kc, z1);  // final step 2046 (look-ahead result discarded)

  // epilogue: ctx = mlp(final params, H[seq[4095]]); out = ctx @ ow^T + ob
  {
    const int ik = seqs[4095];
    const float kq = Hs[ik * 32 + c];
    float a1l[4];
    #pragma unroll
    for (int j = 0; j < 4; ++j)
      a1l[j] = fmaxf(redHalf(W1L[j] * kq) + B1L[j], 0.f);
    float pl = 0.f;
    #pragma unroll
    for (int j = 0; j < 4; ++j) pl = fmaf(W2o[j], a1l[j], pl);
    const float p = (pl + xchg32(pl)) + b2L;
    if (l < 32) ctxs[c] = p;
    __syncthreads();
    float acc = ob[l];
    #pragma unroll
    for (int j = 0; j < 32; ++j) acc = fmaf(OWp[l * 33 + j], ctxs[j], acc);
    out[b * 64 + l] = acc;
  }
}

extern "C" void kernel_launch(void* const* d_in, const int* in_sizes, int n_in,
                              void* d_out, int out_size, void* d_ws, size_t ws_size,
                              hipStream_t stream) {
  const void*  seq   = d_in[0];
  const float* embed = (const float*)d_in[1];
  const float* fw1   = (const float*)d_in[2];
  const float* fb1   = (const float*)d_in[3];
  const float* fw2   = (const float*)d_in[4];
  const float* fb2   = (const float*)d_in[5];
  const float* lng   = (const float*)d_in[6];
  const float* lnb   = (const float*)d_in[7];
  const float* mw1   = (const float*)d_in[8];
  const float* mb1   = (const float*)d_in[9];
  const float* mw2   = (const float*)d_in[10];
  const float* mb2   = (const float*)d_in[11];
  const float* ow    = (const float*)d_in[12];
  const float* ob    = (const float*)d_in[13];
  float* out = (float*)d_out;
  float* H   = (float*)d_ws;  // 64*32 f32 table

  pmm_build_H<<<64, 64, 0, stream>>>(embed, fw1, fb1, fw2, fb2, lng, lnb, H);
  pmm_inner<<<256, 64, 0, stream>>>(seq, H, mw1, mb1, mw2, mb2, ow, ob, out);
}

// Round 14
// 544.232 us; speedup vs baseline: 1.5451x; 1.4242x over previous
//
#include <hip/hip_runtime.h>

#define LN_EPS 1e-5f
// -(LR * 2/H) = -(0.01 * 2/32): folds SGD lr and MSE-mean gradient factor
#define C1 (-6.25e-4f)

typedef unsigned uint2v __attribute__((ext_vector_type(2)));

// ---------- cross-lane helpers ----------
template<int CTRL>
__device__ __forceinline__ float dppAdd(float x) {
  int s = __builtin_amdgcn_update_dpp(0, __float_as_int(x), CTRL, 0xF, 0xF, true);
  return x + __int_as_float(s);
}

// Sum over each 8-lane group (lanes l&~7 .. |7); replicated in the group.
// xor1, xor2 (quad_perm), then row_half_mirror (u -> 7-u within 8): after
// quad-uniformity this adds the other quad. All VALU.
__device__ __forceinline__ float red8(float x) {
  x = dppAdd<0xB1>(x);    // quad_perm(1,0,3,2): xor 1
  x = dppAdd<0x4E>(x);    // quad_perm(2,3,0,1): xor 2
  x = dppAdd<0x141>(x);   // row_half_mirror: cross-quad within 8
  return x;
}

// Lane-exact butterfly adds x[l] + x[l^16] / x[l^32] via permlane*_swap:
// with both operands = x, {r.x,r.y} = {own,partner} per lane (either order),
// so r.x + r.y is the butterfly sum. Sum form HW-validated (r12).
__device__ __forceinline__ float bfly16(float x) {
  uint2v r = __builtin_amdgcn_permlane16_swap(__float_as_uint(x),
                                              __float_as_uint(x), false, false);
  return __uint_as_float(r.x) + __uint_as_float(r.y);
}
__device__ __forceinline__ float bfly32(float x) {
  uint2v r = __builtin_amdgcn_permlane32_swap(__float_as_uint(x),
                                              __float_as_uint(x), false, false);
  return __uint_as_float(r.x) + __uint_as_float(r.y);
}

// Sum across the 8 groups (same u): xor8 (row_ror:8 is exact l^8 within a
// 16-row) + bfly16 + bfly32. Replicated in all 64 lanes.
__device__ __forceinline__ float redG(float x) {
  x = dppAdd<0x128>(x);   // row_ror:8 == xor8 (exact, 16-lane rows)
  x = bfly16(x);
  x = bfly32(x);
  return x;
}

// ---------- kernel A: H[v] = LN(embed[v] + ff(embed[v])), H dim = 32 ----------
__global__ __launch_bounds__(64) void pmm_build_H(
    const float* __restrict__ embed,  // [64][32]
    const float* __restrict__ fw1,    // [64][32]
    const float* __restrict__ fb1,    // [64]
    const float* __restrict__ fw2,    // [32][64]
    const float* __restrict__ fb2,    // [32]
    const float* __restrict__ lng,    // [32]
    const float* __restrict__ lnb,    // [32]
    float* __restrict__ H) {          // [64][32]
  const int v = blockIdx.x;
  const int t = threadIdx.x;
  __shared__ float e[32];
  __shared__ float r1[64];
  if (t < 32) e[t] = embed[v * 32 + t];
  __syncthreads();
  float acc = fb1[t];
  #pragma unroll
  for (int h = 0; h < 32; ++h) acc = fmaf(e[h], fw1[t * 32 + h], acc);
  r1[t] = fmaxf(acc, 0.f);
  __syncthreads();
  if (t < 32) {
    float a2 = fb2[t];
    #pragma unroll
    for (int o = 0; o < 64; ++o) a2 = fmaf(r1[o], fw2[t * 64 + o], a2);
    float z = e[t] + a2;
    float s = z;
    #pragma unroll
    for (int m = 1; m < 32; m <<= 1) s += __shfl_xor(s, m, 64);
    float mu = s * (1.f / 32.f);
    float dz = z - mu;
    float q = dz * dz;
    #pragma unroll
    for (int m = 1; m < 32; m <<= 1) q += __shfl_xor(q, m, 64);
    float var = q * (1.f / 32.f);
    H[v * 32 + t] = dz / sqrtf(var + LN_EPS) * lng[t] + lnb[t];
  }
}

// ---------- kernel B: per-sample inner SGD, 8 groups x 8 lanes ----------
// Group g = l>>3 owns hidden unit g; lane u = l&7 owns columns 4u..4u+3.
// Unit-dim reduces: one red8 covers all 8 units. Column-dim (pred) reduces:
// redG butterfly per column-reg. Look-ahead z1 (r13-validated algebra).
__global__ __launch_bounds__(64) void pmm_inner(
    const void* __restrict__ seq_raw,   // int32 (int64 auto-detected)
    const float* __restrict__ H,        // [64][32] f32 table in ws
    const float* __restrict__ mw1,      // [8][32]
    const float* __restrict__ mb1,      // [8]
    const float* __restrict__ mw2,      // [32][8]
    const float* __restrict__ mb2,      // [32]
    const float* __restrict__ ow,       // [64][32]
    const float* __restrict__ ob,       // [64]
    float* __restrict__ out) {          // [256][64]
  const int b = blockIdx.x;
  const int l = threadIdx.x;    // 0..63
  const int g = l >> 3;         // hidden unit
  const int u = l & 7;          // column quad: cols 4u..4u+3

  __shared__ __align__(16) float Hs[64 * 32];   // 8 KB
  __shared__ int   seqs[4096];                  // 16 KB
  __shared__ float OWp[64 * 33];                // out_w, stride-33 padded
  __shared__ __align__(16) float ctxs[32];

  const int* __restrict__ s32 = (const int*)seq_raw;
  // int64 detection (values 0..63 => odd int32 words all zero under int64).
  int accv = 0;
  #pragma unroll
  for (int q = 0; q < 32; ++q) accv |= s32[2 * (l * 32 + q) + 1];
  const bool is64 = (__ballot(accv != 0) == 0ULL);

  const int base = b * 4096;
  if (!is64) {
    #pragma unroll
    for (int m = 0; m < 16; ++m)
      ((int4*)seqs)[m * 64 + l] = ((const int4*)(s32 + base))[m * 64 + l];
  } else {
    #pragma unroll
    for (int m = 0; m < 64; ++m)
      seqs[m * 64 + l] = s32[(base + m * 64 + l) << 1];  // low word (LE)
  }

  #pragma unroll
  for (int m = 0; m < 8; ++m)
    ((float4*)Hs)[m * 64 + l] = ((const float4*)H)[m * 64 + l];
  #pragma unroll
  for (int m = 0; m < 8; ++m) {
    float4 x = ((const float4*)ow)[m * 64 + l];
    const int idx = (m * 64 + l) * 4;
    const int r = idx >> 5, cc = idx & 31;
    OWp[r * 33 + cc]     = x.x;
    OWp[r * 33 + cc + 1] = x.y;
    OWp[r * 33 + cc + 2] = x.z;
    OWp[r * 33 + cc + 3] = x.w;
  }

  // per-lane parameters
  float W1L[4], W2L[4], b2L[4];
  #pragma unroll
  for (int j = 0; j < 4; ++j) {
    W1L[j] = mw1[g * 32 + 4 * u + j];       // w1[g][4u+j]
    W2L[j] = mw2[(4 * u + j) * 8 + g];      // w2[4u+j][g]
    b2L[j] = mb2[4 * u + j];
  }
  float B1L = mb1[g];
  __syncthreads();

  auto PF = [&](int m, float4& k4, float4& v4) {
    const int ik = seqs[2 * m], iv = seqs[2 * m + 1];
    k4 = ((const float4*)Hs)[ik * 8 + u];
    v4 = ((const float4*)Hs)[iv * 8 + u];
  };

  auto DOT4 = [](const float* w, const float4& x) {
    return fmaf(w[3], x.w, fmaf(w[2], x.z, fmaf(w[1], x.y, w[0] * x.x)));
  };

  // One SGD step; z1 carried (pre-activation of unit g for current k).
  auto STEP = [&](const float4& kc, const float4& vc, const float4& kn,
                  float& z1) {
    // off-path trees (need only step-start state)
    const float s  = red8(fmaf(kc.w, kn.w, fmaf(kc.z, kn.z,
                         fmaf(kc.y, kn.y, kc.x * kn.x))));  // k_m . k_{m+1}
    const float R1 = red8(DOT4(W1L, kn));                   // w1[g] . k_{m+1}
    // serial chain
    const float a1 = fmaxf(z1, 0.f);
    float r0 = redG(W2L[0] * a1) + (b2L[0] - vc.x);
    float r1 = redG(W2L[1] * a1) + (b2L[1] - vc.y);
    float r2 = redG(W2L[2] * a1) + (b2L[2] - vc.z);
    float r3 = redG(W2L[3] * a1) + (b2L[3] - vc.w);
    // m8[g] with OLD w2
    const float m8 = red8(fmaf(W2L[3], r3, fmaf(W2L[2], r2,
                          fmaf(W2L[1], r1, W2L[0] * r0))));
    const float q0 = C1 * r0, q1 = C1 * r1, q2 = C1 * r2, q3 = C1 * r3;
    W2L[0] = fmaf(q0, a1, W2L[0]);
    W2L[1] = fmaf(q1, a1, W2L[1]);
    W2L[2] = fmaf(q2, a1, W2L[2]);
    W2L[3] = fmaf(q3, a1, W2L[3]);
    b2L[0] += q0; b2L[1] += q1; b2L[2] += q2; b2L[3] += q3;
    const float dl = (z1 > 0.f) ? C1 * m8 : 0.f;
    W1L[0] = fmaf(dl, kc.x, W1L[0]);
    W1L[1] = fmaf(dl, kc.y, W1L[1]);
    W1L[2] = fmaf(dl, kc.z, W1L[2]);
    W1L[3] = fmaf(dl, kc.w, W1L[3]);
    z1 = fmaf(dl, s + 1.0f, R1 + B1L);  // z1 for k_{m+1} (old B1)
    B1L += dl;
  };

  // prologue
  float4 kc, vc;
  PF(0, kc, vc);
  float z1 = red8(DOT4(W1L, kc)) + B1L;

  for (int m = 0; m < 2046; ++m) {
    float4 kn, vn;
    PF(m + 1, kn, vn);
    STEP(kc, vc, kn, z1);
    kc = kn; vc = vn;
  }
  STEP(kc, vc, kc, z1);  // step 2046 (look-ahead discarded)

  // epilogue: ctx = mlp(final params, H[seq[4095]]); out = ctx @ ow^T + ob
  {
    const int ik = seqs[4095];
    const float4 kq = ((const float4*)Hs)[ik * 8 + u];
    const float a1 = fmaxf(red8(DOT4(W1L, kq)) + B1L, 0.f);
    float c0 = redG(W2L[0] * a1) + b2L[0];
    float c1 = redG(W2L[1] * a1) + b2L[1];
    float c2 = redG(W2L[2] * a1) + b2L[2];
    float c3 = redG(W2L[3] * a1) + b2L[3];
    if (l < 8) {
      float4 cv; cv.x = c0; cv.y = c1; cv.z = c2; cv.w = c3;
      ((float4*)ctxs)[u] = cv;
    }
    __syncthreads();
    float acc = ob[l];
    #pragma unroll
    for (int j = 0; j < 32; ++j) acc = fmaf(OWp[l * 33 + j], ctxs[j], acc);
    out[b * 64 + l] = acc;
  }
}

extern "C" void kernel_launch(void* const* d_in, const int* in_sizes, int n_in,
                              void* d_out, int out_size, void* d_ws, size_t ws_size,
                              hipStream_t stream) {
  const void*  seq   = d_in[0];
  const float* embed = (const float*)d_in[1];
  const float* fw1   = (const float*)d_in[2];
  const float* fb1   = (const float*)d_in[3];
  const float* fw2   = (const float*)d_in[4];
  const float* fb2   = (const float*)d_in[5];
  const float* lng   = (const float*)d_in[6];
  const float* lnb   = (const float*)d_in[7];
  const float* mw1   = (const float*)d_in[8];
  const float* mb1   = (const float*)d_in[9];
  const float* mw2   = (const float*)d_in[10];
  const float* mb2   = (const float*)d_in[11];
  const float* ow    = (const float*)d_in[12];
  const float* ob    = (const float*)d_in[13];
  float* out = (float*)d_out;
  float* H   = (float*)d_ws;  // 64*32 f32 table

  pmm_build_H<<<64, 64, 0, stream>>>(embed, fw1, fb1, fw2, fb2, lng, lnb, H);
  pmm_inner<<<256, 64, 0, stream>>>(seq, H, mw1, mb1, mw2, mb2, ow, ob, out);
}